// Round 6
// baseline (343.545 us; speedup 1.0000x reference)
//
#include <hip/hip_runtime.h>
#include <hip/hip_bf16.h>

// Mapper: 4 per-word GEMM layers with LN+LeakyReLU between.
// Round 6: LDS-pipe was the saturated resource (48 b128 ops/block-step vs
// 154 cyc of MFMA). New structure: A-fragments load global->register directly
// (k-contiguous 16B chunks, L2-resident), LDS holds ONLY the transposed B
// tile (20 ops/block-step). BM=128, BN=64, BK=32, 4 waves of 32x64.

typedef unsigned short u16;
typedef __attribute__((ext_vector_type(8))) short bf16x8;
typedef __attribute__((ext_vector_type(4))) float f32x4;

constexpr int CB = 256;      // batch
constexpr int CW = 20;       // words
constexpr int CDIN = 1024;
constexpr int CDOUT = 1024;
constexpr int CH = 1280;
constexpr float CEPS = 1e-5f;
constexpr float CSLOPE = 0.01f;

__device__ __forceinline__ u16 f2bf(float f) {
    union { float f; unsigned u; } v; v.f = f;
    unsigned r = v.u + 0x7fffu + ((v.u >> 16) & 1u);
    return (u16)(r >> 16);
}
// packed pair via HW v_cvt_pk_bf16_f32
__device__ __forceinline__ unsigned pk2(float a, float b) {
    __hip_bfloat162 h = __float22bfloat162_rn(float2{a, b});
    union { __hip_bfloat162 h; unsigned u; } v; v.h = h;
    return v.u;
}
__device__ __forceinline__ bf16x8 pack8(float4 a, float4 b) {
    union { unsigned u[4]; bf16x8 v; } r;
    r.u[0] = pk2(a.x, a.y); r.u[1] = pk2(a.z, a.w);
    r.u[2] = pk2(b.x, b.y); r.u[3] = pk2(b.z, b.w);
    return r.v;
}

// Workgroup barrier without the vmcnt(0) drain (LDS-visibility only).
__device__ __forceinline__ void bar_keep_vmem() {
    asm volatile("s_waitcnt lgkmcnt(0)" ::: "memory");
    __builtin_amdgcn_s_barrier();
    __builtin_amdgcn_sched_barrier(0);
}

// ---------------------------------------------------------------------------
// GEMM: out[b, w, n] = sum_k A[b, w, k] * Bw[w, k, n] + bias[w, n]
// A: bf16 (u16) or fp32 (AF32), row (b*CW+w), K-contiguous.  Bw: fp32 [W][K][N].
// Tile: BM=128, BN=64, BK=32. 4 waves stacked in M, wave-tile 32x64
// = 2(m) x 4(n) MFMA 16x16x32 tiles = 8 MFMA/wave/step.
// A-fragments: global->reg direct (no LDS), 1-step prefetch, L2-served.
// B: depth-2 register prefetch -> cvt_pk -> LDS [n][k] stride 40 u16.
// Grid: 2 * (N/64) * CW blocks, XCD-swizzled, mb fastest.
// ---------------------------------------------------------------------------
template <int K, int N, bool AF32>
__global__ __launch_bounds__(256, 4) void gemm_kernel(
    const void* __restrict__ Aptr, const float* __restrict__ Bw,
    const float* __restrict__ bias, float* __restrict__ Out)
{
    constexpr int NB  = N / 64;
    constexpr int NK  = K / 32;          // 32 or 40, even
    constexpr int NWG = 2 * NB * CW;
    constexpr int CPX = NWG / 8;

    __shared__ u16 Bs[2][64 * 40];

    const int t   = threadIdx.x;
    const int bid = blockIdx.x;
    const int logical = (bid & 7) * CPX + (bid >> 3);
    const int mb = logical & 1;
    const int nb = (logical >> 1) % NB;
    const int w  = logical / (2 * NB);

    const int m0g = mb * 128;
    const int n0g = nb * 64;

    const int lane = t & 63;
    const int wid  = t >> 6;
    const int lrow = lane & 15;
    const int kg   = lane >> 4;          // 0..3

    // A-fragment base pointers: frag i row = m0g + wid*32 + i*16 + lrow,
    // k-chunk kg*8 (16B contiguous). Step offset folds into the immediate.
    const int r0 = m0g + wid * 32 + lrow;
    const u16*   a0p  = (const u16*)Aptr   + ((size_t)r0 * CW + w) * K + kg * 8;
    const u16*   a1p  = (const u16*)Aptr   + ((size_t)(r0 + 16) * CW + w) * K + kg * 8;
    const float* a0pf = (const float*)Aptr + ((size_t)r0 * CW + w) * K + kg * 8;
    const float* a1pf = (const float*)Aptr + ((size_t)(r0 + 16) * CW + w) * K + kg * 8;

    // B staging: thread -> (n = t&63, k-rows (t>>6)*8 .. +7), dword stride N
    const int bn = t & 63;
    const int bq = t >> 6;
    const float* bgp = Bw + (size_t)w * K * N + (size_t)bq * 8 * N + (n0g + bn);
    const int bwoff = bn * 40 + bq * 8;

    f32x4 acc[2][4];
    #pragma unroll
    for (int i = 0; i < 2; ++i)
        #pragma unroll
        for (int j = 0; j < 4; ++j)
            acc[i][j] = (f32x4){0.f, 0.f, 0.f, 0.f};

    // prefetch slots — static names only
    uint4  ar_A_0, ar_A_1, ar_B_0, ar_B_1;                 // bf16 A frags
    float4 af_A_0a, af_A_0b, af_A_1a, af_A_1b;             // fp32 A frags (L1)
    float4 af_B_0a, af_B_0b, af_B_1a, af_B_1b;
    float  b_s0_0, b_s0_1, b_s0_2, b_s0_3, b_s0_4, b_s0_5, b_s0_6, b_s0_7;
    float  b_s1_0, b_s1_1, b_s1_2, b_s1_3, b_s1_4, b_s1_5, b_s1_6, b_s1_7;

#define LOADAF(k0, SL)                                                        \
    do {                                                                      \
        if constexpr (AF32) {                                                 \
            af_##SL##_0a = *reinterpret_cast<const float4*>(a0pf + (k0));     \
            af_##SL##_0b = *reinterpret_cast<const float4*>(a0pf + (k0) + 4); \
            af_##SL##_1a = *reinterpret_cast<const float4*>(a1pf + (k0));     \
            af_##SL##_1b = *reinterpret_cast<const float4*>(a1pf + (k0) + 4); \
        } else {                                                              \
            ar_##SL##_0 = *reinterpret_cast<const uint4*>(a0p + (k0));        \
            ar_##SL##_1 = *reinterpret_cast<const uint4*>(a1p + (k0));        \
        }                                                                     \
    } while (0)

#define LOADB(k0, SL)                                                         \
    do {                                                                      \
        const float* p = bgp + (size_t)(k0) * N;                              \
        b_s##SL##_0 = p[0];               b_s##SL##_1 = p[(size_t)1 * N];     \
        b_s##SL##_2 = p[(size_t)2 * N];   b_s##SL##_3 = p[(size_t)3 * N];     \
        b_s##SL##_4 = p[(size_t)4 * N];   b_s##SL##_5 = p[(size_t)5 * N];     \
        b_s##SL##_6 = p[(size_t)6 * N];   b_s##SL##_7 = p[(size_t)7 * N];     \
    } while (0)

#define WRITEB(buf, SL)                                                       \
    do {                                                                      \
        uint4 q;                                                              \
        q.x = pk2(b_s##SL##_0, b_s##SL##_1);                                  \
        q.y = pk2(b_s##SL##_2, b_s##SL##_3);                                  \
        q.z = pk2(b_s##SL##_4, b_s##SL##_5);                                  \
        q.w = pk2(b_s##SL##_6, b_s##SL##_7);                                  \
        *reinterpret_cast<uint4*>(&Bs[buf][bwoff]) = q;                       \
    } while (0)

#define COMPUTE(buf, SL)                                                      \
    do {                                                                      \
        bf16x8 a0f, a1f;                                                      \
        if constexpr (AF32) {                                                 \
            a0f = pack8(af_##SL##_0a, af_##SL##_0b);                          \
            a1f = pack8(af_##SL##_1a, af_##SL##_1b);                          \
        } else {                                                              \
            a0f = __builtin_bit_cast(bf16x8, ar_##SL##_0);                    \
            a1f = __builtin_bit_cast(bf16x8, ar_##SL##_1);                    \
        }                                                                     \
        bf16x8 bf0 = *reinterpret_cast<const bf16x8*>(                        \
            &Bs[buf][(0 * 16 + lrow) * 40 + kg * 8]);                         \
        bf16x8 bf1 = *reinterpret_cast<const bf16x8*>(                        \
            &Bs[buf][(1 * 16 + lrow) * 40 + kg * 8]);                         \
        bf16x8 bf2 = *reinterpret_cast<const bf16x8*>(                        \
            &Bs[buf][(2 * 16 + lrow) * 40 + kg * 8]);                         \
        bf16x8 bf3 = *reinterpret_cast<const bf16x8*>(                        \
            &Bs[buf][(3 * 16 + lrow) * 40 + kg * 8]);                         \
        acc[0][0] = __builtin_amdgcn_mfma_f32_16x16x32_bf16(a0f, bf0, acc[0][0], 0, 0, 0); \
        acc[1][0] = __builtin_amdgcn_mfma_f32_16x16x32_bf16(a1f, bf0, acc[1][0], 0, 0, 0); \
        acc[0][1] = __builtin_amdgcn_mfma_f32_16x16x32_bf16(a0f, bf1, acc[0][1], 0, 0, 0); \
        acc[1][1] = __builtin_amdgcn_mfma_f32_16x16x32_bf16(a1f, bf1, acc[1][1], 0, 0, 0); \
        acc[0][2] = __builtin_amdgcn_mfma_f32_16x16x32_bf16(a0f, bf2, acc[0][2], 0, 0, 0); \
        acc[1][2] = __builtin_amdgcn_mfma_f32_16x16x32_bf16(a1f, bf2, acc[1][2], 0, 0, 0); \
        acc[0][3] = __builtin_amdgcn_mfma_f32_16x16x32_bf16(a0f, bf3, acc[0][3], 0, 0, 0); \
        acc[1][3] = __builtin_amdgcn_mfma_f32_16x16x32_bf16(a1f, bf3, acc[1][3], 0, 0, 0); \
    } while (0)

    // prologue: B slots <- steps 0,1; A frags <- step 0; LDS buf0 <- step 0
    LOADB(0, 0);
    LOADB(32, 1);
    LOADAF(0, A);
    WRITEB(0, 0);
    bar_keep_vmem();

    for (int ks = 0; ks < NK; ks += 2) {
        // phase A: compute step ks from buf0 + A-slot A
        if (ks + 2 < NK) LOADB((ks + 2) * 32, 0);
        LOADAF((ks + 1) * 32, B);
        COMPUTE(0, A);
        WRITEB(1, 1);
        bar_keep_vmem();

        // phase B: compute step ks+1 from buf1 + A-slot B
        if (ks + 3 < NK) LOADB((ks + 3) * 32, 1);
        if (ks + 2 < NK) LOADAF((ks + 2) * 32, A);
        COMPUTE(1, B);
        if (ks + 2 < NK) WRITEB(0, 0);
        bar_keep_vmem();
    }

    // epilogue: + bias, store fp32
    const int rb = (lane >> 4) * 4;
    #pragma unroll
    for (int j = 0; j < 4; ++j) {
        const int gn = n0g + j * 16 + lrow;
        const float bv = bias[(size_t)w * N + gn];
        #pragma unroll
        for (int i = 0; i < 2; ++i) {
            const int gm = m0g + wid * 32 + i * 16 + rb;
            #pragma unroll
            for (int r = 0; r < 4; ++r) {
                Out[((size_t)(gm + r) * CW + w) * N + gn] = acc[i][j][r] + bv;
            }
        }
    }
#undef LOADAF
#undef LOADB
#undef WRITEB
#undef COMPUTE
}

// ---------------------------------------------------------------------------
// LayerNorm + LeakyReLU over last dim (H=1280), writes bf16.
// ---------------------------------------------------------------------------
__global__ __launch_bounds__(320) void ln_lrelu_kernel(
    const float* __restrict__ h, const float* __restrict__ g,
    const float* __restrict__ bta, u16* __restrict__ out)
{
    const int row = blockIdx.x;          // b*CW + w
    const int w = row % CW;
    const int t = threadIdx.x;

    const float4 v = reinterpret_cast<const float4*>(h + (size_t)row * CH)[t];
    float s  = v.x + v.y + v.z + v.w;
    float sq = v.x * v.x + v.y * v.y + v.z * v.z + v.w * v.w;
    #pragma unroll
    for (int o = 32; o > 0; o >>= 1) {
        s  += __shfl_down(s, o, 64);
        sq += __shfl_down(sq, o, 64);
    }
    __shared__ float ss[5], sg[5];
    const int lane = t & 63, wv = t >> 6;
    if (lane == 0) { ss[wv] = s; sg[wv] = sq; }
    __syncthreads();
    float S = 0.f, Q = 0.f;
    #pragma unroll
    for (int i = 0; i < 5; ++i) { S += ss[i]; Q += sg[i]; }
    const float mean = S * (1.0f / CH);
    const float var  = Q * (1.0f / CH) - mean * mean;
    const float rstd = rsqrtf(var + CEPS);

    const float4 gg = reinterpret_cast<const float4*>(g   + (size_t)w * CH)[t];
    const float4 bb = reinterpret_cast<const float4*>(bta + (size_t)w * CH)[t];
    float4 y;
    y.x = (v.x - mean) * rstd * gg.x + bb.x;
    y.y = (v.y - mean) * rstd * gg.y + bb.y;
    y.z = (v.z - mean) * rstd * gg.z + bb.z;
    y.w = (v.w - mean) * rstd * gg.w + bb.w;
    y.x = y.x >= 0.f ? y.x : CSLOPE * y.x;
    y.y = y.y >= 0.f ? y.y : CSLOPE * y.y;
    y.z = y.z >= 0.f ? y.z : CSLOPE * y.z;
    y.w = y.w >= 0.f ? y.w : CSLOPE * y.w;
    ushort4 o4;
    o4.x = f2bf(y.x); o4.y = f2bf(y.y); o4.z = f2bf(y.z); o4.w = f2bf(y.w);
    reinterpret_cast<ushort4*>(out + (size_t)row * CH)[t] = o4;
}

extern "C" void kernel_launch(void* const* d_in, const int* in_sizes, int n_in,
                              void* d_out, int out_size, void* d_ws, size_t ws_size,
                              hipStream_t stream)
{
    const float* embs = (const float*)d_in[0];
    const float* W1  = (const float*)d_in[1];
    const float* b1  = (const float*)d_in[2];
    const float* g1  = (const float*)d_in[3];
    const float* bn1 = (const float*)d_in[4];
    const float* W2  = (const float*)d_in[5];
    const float* b2  = (const float*)d_in[6];
    const float* g2  = (const float*)d_in[7];
    const float* bn2 = (const float*)d_in[8];
    const float* W3  = (const float*)d_in[9];
    const float* b3  = (const float*)d_in[10];
    const float* g3  = (const float*)d_in[11];
    const float* bn3 = (const float*)d_in[12];
    const float* W4  = (const float*)d_in[13];
    const float* b4  = (const float*)d_in[14];

    char* ws = (char*)d_ws;
    float* h_raw = (float*)ws;                               // B*W*H*4  = 26,214,400
    u16*   a_bf  = (u16*)(ws + 26214400);                    // B*W*H*2  = 13,107,200

    // Layer 1: [256x1024] @ [1024x1280], A = embs fp32 (cvt at consume)
    gemm_kernel<CDIN, CH, true><<<2 * (CH / 64) * CW, 256, 0, stream>>>(embs, W1, b1, h_raw);
    ln_lrelu_kernel<<<CB * CW, 320, 0, stream>>>(h_raw, g1, bn1, a_bf);
    // Layer 2: [256x1280] @ [1280x1280]
    gemm_kernel<CH, CH, false><<<2 * (CH / 64) * CW, 256, 0, stream>>>(a_bf, W2, b2, h_raw);
    ln_lrelu_kernel<<<CB * CW, 320, 0, stream>>>(h_raw, g2, bn2, a_bf);
    // Layer 3: [256x1280] @ [1280x1280]
    gemm_kernel<CH, CH, false><<<2 * (CH / 64) * CW, 256, 0, stream>>>(a_bf, W3, b3, h_raw);
    ln_lrelu_kernel<<<CB * CW, 320, 0, stream>>>(h_raw, g3, bn3, a_bf);
    // Layer 4: [256x1280] @ [1280x1024] -> d_out (fp32)
    gemm_kernel<CH, CDOUT, false><<<2 * (CDOUT / 64) * CW, 256, 0, stream>>>(a_bf, W4, b4, (float*)d_out);
}

// Round 8
// 331.455 us; speedup vs baseline: 1.0365x; 1.0365x over previous
//
#include <hip/hip_runtime.h>
#include <hip/hip_bf16.h>

// Mapper: 4 per-word GEMM layers with LN+LeakyReLU between.
// Round 8 (= R7 with macro-shadowing compile fix): R6 geometry (BM=128,BN=64,
// BK=32; A global->reg, B-only LDS) with prefetch DEPTH raised past the
// latencies: B depth-4 (issue->LDS-write gap ~3 phases > 900cyc HBM miss),
// A depth-2 (>= L2 latency). NK % 4 == 0.

typedef unsigned short u16;
typedef __attribute__((ext_vector_type(8))) short bf16x8;
typedef __attribute__((ext_vector_type(4))) float f32x4;

constexpr int CB = 256;      // batch
constexpr int CW = 20;       // words
constexpr int CDIN = 1024;
constexpr int CDOUT = 1024;
constexpr int CH = 1280;
constexpr float CEPS = 1e-5f;
constexpr float CSLOPE = 0.01f;

__device__ __forceinline__ u16 f2bf(float f) {
    union { float f; unsigned u; } v; v.f = f;
    unsigned r = v.u + 0x7fffu + ((v.u >> 16) & 1u);
    return (u16)(r >> 16);
}
// packed pair via HW v_cvt_pk_bf16_f32
__device__ __forceinline__ unsigned pk2(float a, float b) {
    __hip_bfloat162 h = __float22bfloat162_rn(float2{a, b});
    union { __hip_bfloat162 h; unsigned u; } v; v.h = h;
    return v.u;
}
__device__ __forceinline__ bf16x8 pack8(float4 a, float4 b) {
    union { unsigned u[4]; bf16x8 v; } r;
    r.u[0] = pk2(a.x, a.y); r.u[1] = pk2(a.z, a.w);
    r.u[2] = pk2(b.x, b.y); r.u[3] = pk2(b.z, b.w);
    return r.v;
}

// Workgroup barrier without the vmcnt(0) drain (LDS-visibility only).
__device__ __forceinline__ void bar_keep_vmem() {
    asm volatile("s_waitcnt lgkmcnt(0)" ::: "memory");
    __builtin_amdgcn_s_barrier();
    __builtin_amdgcn_sched_barrier(0);
}

// ---------------------------------------------------------------------------
// GEMM: out[b, w, n] = sum_k A[b, w, k] * Bw[w, k, n] + bias[w, n]
// A: bf16 (u16) or fp32 (AF32), row (b*CW+w), K-contiguous.  Bw: fp32 [W][K][N].
// Tile: BM=128, BN=64, BK=32. 4 waves stacked in M, wave-tile 32x64
// = 2(m) x 4(n) MFMA 16x16x32 = 8 MFMA/wave/step.
// B: 4 register slots -> cvt_pk -> LDS [n][k] stride 40 u16, double-buffered.
// A: 2 parity register slots, global->reg direct (L2-served via XCD swizzle).
// Grid: 2 * (N/64) * CW blocks, XCD-swizzled, mb fastest.
// ---------------------------------------------------------------------------
template <int K, int N, bool AF32>
__global__ __launch_bounds__(256, 2) void gemm_kernel(
    const void* __restrict__ Aptr, const float* __restrict__ Bw,
    const float* __restrict__ bias, float* __restrict__ Out)
{
    constexpr int NB  = N / 64;
    constexpr int NK  = K / 32;          // 32 or 40 (divisible by 4)
    static_assert(NK % 4 == 0 && NK >= 8, "NK must be multiple of 4");
    constexpr int NWG = 2 * NB * CW;
    constexpr int CPX = NWG / 8;

    __shared__ u16 Bs[2][64 * 40];

    const int t   = threadIdx.x;
    const int bid = blockIdx.x;
    const int logical = (bid & 7) * CPX + (bid >> 3);
    const int mb = logical & 1;
    const int nb = (logical >> 1) % NB;
    const int w  = logical / (2 * NB);

    const int m0g = mb * 128;
    const int n0g = nb * 64;

    const int lane = t & 63;
    const int wid  = t >> 6;
    const int lrow = lane & 15;
    const int kg   = lane >> 4;          // 0..3

    // A-fragment base pointers (16B contiguous k-chunks per lane).
    const int r0 = m0g + wid * 32 + lrow;
    const u16*   a0p  = (const u16*)Aptr   + ((size_t)r0 * CW + w) * K + kg * 8;
    const u16*   a1p  = (const u16*)Aptr   + ((size_t)(r0 + 16) * CW + w) * K + kg * 8;
    const float* a0pf = (const float*)Aptr + ((size_t)r0 * CW + w) * K + kg * 8;
    const float* a1pf = (const float*)Aptr + ((size_t)(r0 + 16) * CW + w) * K + kg * 8;

    // B staging: thread -> (n = t&63, k-rows wid*8 .. +7), dword stride N
    const int bn = t & 63;
    const float* bgp = Bw + (size_t)w * K * N + (size_t)wid * 8 * N + (n0g + bn);
    const int bwoff = bn * 40 + wid * 8;

    f32x4 acc[2][4];
    #pragma unroll
    for (int i = 0; i < 2; ++i)
        #pragma unroll
        for (int j = 0; j < 4; ++j)
            acc[i][j] = (f32x4){0.f, 0.f, 0.f, 0.f};

    // prefetch slots — static names only
    uint4  ar_A_0, ar_A_1, ar_B_0, ar_B_1;                 // bf16 A frags
    float4 af_A_0a, af_A_0b, af_A_1a, af_A_1b;             // fp32 A frags (L1)
    float4 af_B_0a, af_B_0b, af_B_1a, af_B_1b;
    float  b_s0_0, b_s0_1, b_s0_2, b_s0_3, b_s0_4, b_s0_5, b_s0_6, b_s0_7;
    float  b_s1_0, b_s1_1, b_s1_2, b_s1_3, b_s1_4, b_s1_5, b_s1_6, b_s1_7;
    float  b_s2_0, b_s2_1, b_s2_2, b_s2_3, b_s2_4, b_s2_5, b_s2_6, b_s2_7;
    float  b_s3_0, b_s3_1, b_s3_2, b_s3_3, b_s3_4, b_s3_5, b_s3_6, b_s3_7;

#define LOADAF(k0, SL)                                                        \
    do {                                                                      \
        if constexpr (AF32) {                                                 \
            af_##SL##_0a = *reinterpret_cast<const float4*>(a0pf + (k0));     \
            af_##SL##_0b = *reinterpret_cast<const float4*>(a0pf + (k0) + 4); \
            af_##SL##_1a = *reinterpret_cast<const float4*>(a1pf + (k0));     \
            af_##SL##_1b = *reinterpret_cast<const float4*>(a1pf + (k0) + 4); \
        } else {                                                              \
            ar_##SL##_0 = *reinterpret_cast<const uint4*>(a0p + (k0));        \
            ar_##SL##_1 = *reinterpret_cast<const uint4*>(a1p + (k0));        \
        }                                                                     \
    } while (0)

#define LOADB(k0, SL)                                                         \
    do {                                                                      \
        const float* _pB = bgp + (size_t)(k0) * N;                            \
        b_s##SL##_0 = _pB[0];               b_s##SL##_1 = _pB[(size_t)1 * N]; \
        b_s##SL##_2 = _pB[(size_t)2 * N];   b_s##SL##_3 = _pB[(size_t)3 * N]; \
        b_s##SL##_4 = _pB[(size_t)4 * N];   b_s##SL##_5 = _pB[(size_t)5 * N]; \
        b_s##SL##_6 = _pB[(size_t)6 * N];   b_s##SL##_7 = _pB[(size_t)7 * N]; \
    } while (0)

#define WRITEB(buf, SL)                                                       \
    do {                                                                      \
        uint4 q;                                                              \
        q.x = pk2(b_s##SL##_0, b_s##SL##_1);                                  \
        q.y = pk2(b_s##SL##_2, b_s##SL##_3);                                  \
        q.z = pk2(b_s##SL##_4, b_s##SL##_5);                                  \
        q.w = pk2(b_s##SL##_6, b_s##SL##_7);                                  \
        *reinterpret_cast<uint4*>(&Bs[buf][bwoff]) = q;                       \
    } while (0)

#define COMPUTE(buf, SL)                                                      \
    do {                                                                      \
        bf16x8 a0f, a1f;                                                      \
        if constexpr (AF32) {                                                 \
            a0f = pack8(af_##SL##_0a, af_##SL##_0b);                          \
            a1f = pack8(af_##SL##_1a, af_##SL##_1b);                          \
        } else {                                                              \
            a0f = __builtin_bit_cast(bf16x8, ar_##SL##_0);                    \
            a1f = __builtin_bit_cast(bf16x8, ar_##SL##_1);                    \
        }                                                                     \
        bf16x8 bf0 = *reinterpret_cast<const bf16x8*>(                        \
            &Bs[buf][(0 * 16 + lrow) * 40 + kg * 8]);                         \
        bf16x8 bf1 = *reinterpret_cast<const bf16x8*>(                        \
            &Bs[buf][(1 * 16 + lrow) * 40 + kg * 8]);                         \
        bf16x8 bf2 = *reinterpret_cast<const bf16x8*>(                        \
            &Bs[buf][(2 * 16 + lrow) * 40 + kg * 8]);                         \
        bf16x8 bf3 = *reinterpret_cast<const bf16x8*>(                        \
            &Bs[buf][(3 * 16 + lrow) * 40 + kg * 8]);                         \
        acc[0][0] = __builtin_amdgcn_mfma_f32_16x16x32_bf16(a0f, bf0, acc[0][0], 0, 0, 0); \
        acc[1][0] = __builtin_amdgcn_mfma_f32_16x16x32_bf16(a1f, bf0, acc[1][0], 0, 0, 0); \
        acc[0][1] = __builtin_amdgcn_mfma_f32_16x16x32_bf16(a0f, bf1, acc[0][1], 0, 0, 0); \
        acc[1][1] = __builtin_amdgcn_mfma_f32_16x16x32_bf16(a1f, bf1, acc[1][1], 0, 0, 0); \
        acc[0][2] = __builtin_amdgcn_mfma_f32_16x16x32_bf16(a0f, bf2, acc[0][2], 0, 0, 0); \
        acc[1][2] = __builtin_amdgcn_mfma_f32_16x16x32_bf16(a1f, bf2, acc[1][2], 0, 0, 0); \
        acc[0][3] = __builtin_amdgcn_mfma_f32_16x16x32_bf16(a0f, bf3, acc[0][3], 0, 0, 0); \
        acc[1][3] = __builtin_amdgcn_mfma_f32_16x16x32_bf16(a1f, bf3, acc[1][3], 0, 0, 0); \
    } while (0)

    // prologue: B slots <- steps 0..3; A slots <- steps 0,1; LDS buf0 <- 0
    LOADB(0 * 32, 0); LOADB(1 * 32, 1); LOADB(2 * 32, 2); LOADB(3 * 32, 3);
    LOADAF(0 * 32, A); LOADAF(1 * 32, B);
    WRITEB(0, 0);                        // counted vmcnt wait on slot-0 only
    bar_keep_vmem();

    for (int p = 0; p < NK; p += 4) {
        // q = p+0: consume buf0/slotA; stage slot1 -> buf1; refill slot0
        if (p + 4 < NK) LOADB((p + 4) * 32, 0);
        COMPUTE(0, A);
        if (p + 2 < NK) LOADAF((p + 2) * 32, A);
        if (p + 1 < NK) WRITEB(1, 1);
        bar_keep_vmem();

        // q = p+1: consume buf1/slotB; stage slot2 -> buf0; refill slot1
        if (p + 5 < NK) LOADB((p + 5) * 32, 1);
        COMPUTE(1, B);
        if (p + 3 < NK) LOADAF((p + 3) * 32, B);
        if (p + 2 < NK) WRITEB(0, 2);
        bar_keep_vmem();

        // q = p+2: consume buf0/slotA; stage slot3 -> buf1; refill slot2
        if (p + 6 < NK) LOADB((p + 6) * 32, 2);
        COMPUTE(0, A);
        if (p + 4 < NK) LOADAF((p + 4) * 32, A);
        if (p + 3 < NK) WRITEB(1, 3);
        bar_keep_vmem();

        // q = p+3: consume buf1/slotB; stage slot0 -> buf0; refill slot3
        if (p + 7 < NK) LOADB((p + 7) * 32, 3);
        COMPUTE(1, B);
        if (p + 5 < NK) LOADAF((p + 5) * 32, B);
        if (p + 4 < NK) WRITEB(0, 0);
        bar_keep_vmem();
    }

    // epilogue: + bias, store fp32
    const int rb = (lane >> 4) * 4;
    #pragma unroll
    for (int j = 0; j < 4; ++j) {
        const int gn = n0g + j * 16 + lrow;
        const float bv = bias[(size_t)w * N + gn];
        #pragma unroll
        for (int i = 0; i < 2; ++i) {
            const int gm = m0g + wid * 32 + i * 16 + rb;
            #pragma unroll
            for (int r = 0; r < 4; ++r) {
                Out[((size_t)(gm + r) * CW + w) * N + gn] = acc[i][j][r] + bv;
            }
        }
    }
#undef LOADAF
#undef LOADB
#undef WRITEB
#undef COMPUTE
}

// ---------------------------------------------------------------------------
// LayerNorm + LeakyReLU over last dim (H=1280), writes bf16.
// ---------------------------------------------------------------------------
__global__ __launch_bounds__(320) void ln_lrelu_kernel(
    const float* __restrict__ h, const float* __restrict__ g,
    const float* __restrict__ bta, u16* __restrict__ out)
{
    const int row = blockIdx.x;          // b*CW + w
    const int w = row % CW;
    const int t = threadIdx.x;

    const float4 v = reinterpret_cast<const float4*>(h + (size_t)row * CH)[t];
    float s  = v.x + v.y + v.z + v.w;
    float sq = v.x * v.x + v.y * v.y + v.z * v.z + v.w * v.w;
    #pragma unroll
    for (int o = 32; o > 0; o >>= 1) {
        s  += __shfl_down(s, o, 64);
        sq += __shfl_down(sq, o, 64);
    }
    __shared__ float ss[5], sg[5];
    const int lane = t & 63, wv = t >> 6;
    if (lane == 0) { ss[wv] = s; sg[wv] = sq; }
    __syncthreads();
    float S = 0.f, Q = 0.f;
    #pragma unroll
    for (int i = 0; i < 5; ++i) { S += ss[i]; Q += sg[i]; }
    const float mean = S * (1.0f / CH);
    const float var  = Q * (1.0f / CH) - mean * mean;
    const float rstd = rsqrtf(var + CEPS);

    const float4 gg = reinterpret_cast<const float4*>(g   + (size_t)w * CH)[t];
    const float4 bb = reinterpret_cast<const float4*>(bta + (size_t)w * CH)[t];
    float4 y;
    y.x = (v.x - mean) * rstd * gg.x + bb.x;
    y.y = (v.y - mean) * rstd * gg.y + bb.y;
    y.z = (v.z - mean) * rstd * gg.z + bb.z;
    y.w = (v.w - mean) * rstd * gg.w + bb.w;
    y.x = y.x >= 0.f ? y.x : CSLOPE * y.x;
    y.y = y.y >= 0.f ? y.y : CSLOPE * y.y;
    y.z = y.z >= 0.f ? y.z : CSLOPE * y.z;
    y.w = y.w >= 0.f ? y.w : CSLOPE * y.w;
    ushort4 o4;
    o4.x = f2bf(y.x); o4.y = f2bf(y.y); o4.z = f2bf(y.z); o4.w = f2bf(y.w);
    reinterpret_cast<ushort4*>(out + (size_t)row * CH)[t] = o4;
}

extern "C" void kernel_launch(void* const* d_in, const int* in_sizes, int n_in,
                              void* d_out, int out_size, void* d_ws, size_t ws_size,
                              hipStream_t stream)
{
    const float* embs = (const float*)d_in[0];
    const float* W1  = (const float*)d_in[1];
    const float* b1  = (const float*)d_in[2];
    const float* g1  = (const float*)d_in[3];
    const float* bn1 = (const float*)d_in[4];
    const float* W2  = (const float*)d_in[5];
    const float* b2  = (const float*)d_in[6];
    const float* g2  = (const float*)d_in[7];
    const float* bn2 = (const float*)d_in[8];
    const float* W3  = (const float*)d_in[9];
    const float* b3  = (const float*)d_in[10];
    const float* g3  = (const float*)d_in[11];
    const float* bn3 = (const float*)d_in[12];
    const float* W4  = (const float*)d_in[13];
    const float* b4  = (const float*)d_in[14];

    char* ws = (char*)d_ws;
    float* h_raw = (float*)ws;                               // B*W*H*4  = 26,214,400
    u16*   a_bf  = (u16*)(ws + 26214400);                    // B*W*H*2  = 13,107,200

    // Layer 1: [256x1024] @ [1024x1280], A = embs fp32 (cvt at consume)
    gemm_kernel<CDIN, CH, true><<<2 * (CH / 64) * CW, 256, 0, stream>>>(embs, W1, b1, h_raw);
    ln_lrelu_kernel<<<CB * CW, 320, 0, stream>>>(h_raw, g1, bn1, a_bf);
    // Layer 2: [256x1280] @ [1280x1280]
    gemm_kernel<CH, CH, false><<<2 * (CH / 64) * CW, 256, 0, stream>>>(a_bf, W2, b2, h_raw);
    ln_lrelu_kernel<<<CB * CW, 320, 0, stream>>>(h_raw, g2, bn2, a_bf);
    // Layer 3: [256x1280] @ [1280x1280]
    gemm_kernel<CH, CH, false><<<2 * (CH / 64) * CW, 256, 0, stream>>>(a_bf, W3, b3, h_raw);
    ln_lrelu_kernel<<<CB * CW, 320, 0, stream>>>(h_raw, g3, bn3, a_bf);
    // Layer 4: [256x1280] @ [1280x1024] -> d_out (fp32)
    gemm_kernel<CH, CDOUT, false><<<2 * (CDOUT / 64) * CW, 256, 0, stream>>>(a_bf, W4, b4, (float*)d_out);
}